// Round 5
// baseline (1091.847 us; speedup 1.0000x reference)
//
#include <hip/hip_runtime.h>
#include <hip/hip_bf16.h>

typedef __bf16 bf16x8 __attribute__((ext_vector_type(8)));
typedef float  f32x4  __attribute__((ext_vector_type(4)));

#define MFMA16(a,b,c) __builtin_amdgcn_mfma_f32_16x16x32_bf16((a),(b),(c),0,0,0)

#if __has_builtin(__builtin_amdgcn_exp2f)
#define EXP2(x) __builtin_amdgcn_exp2f(x)
#else
#define EXP2(x) exp2f(x)
#endif
#define RCP(x) __builtin_amdgcn_rcpf(x)

#define KL  1.44269504088896340736f   /* log2(e)   */
#define K2L 2.88539008177792681472f   /* 2*log2(e) */

__device__ __forceinline__ bf16x8 cvt8(f32x4 a, f32x4 b){
  bf16x8 r;
  r[0]=(__bf16)a[0]; r[1]=(__bf16)a[1]; r[2]=(__bf16)a[2]; r[3]=(__bf16)a[3];
  r[4]=(__bf16)b[0]; r[5]=(__bf16)b[1]; r[6]=(__bf16)b[2]; r[7]=(__bf16)b[3];
  return r;
}
__device__ __forceinline__ f32x4 sp(float v){ return (f32x4){v,v,v,v}; }
__device__ __forceinline__ bf16x8 ld8(const float* p){
  return cvt8(*(const f32x4*)p, *(const f32x4*)(p+4));
}
// scaled load: 8 f32 -> *s -> bf16x8  (gate weights pre-scaled by log2e)
__device__ __forceinline__ bf16x8 ld8s(const float* p, float s){
  f32x4 a = *(const f32x4*)p, b = *(const f32x4*)(p+4);
  return cvt8(a*sp(s), b*sp(s));
}

// LSTM elementwise with PRE-SCALED gates (validated R3/R4, same absmax):
// 5 exp2 + 3 rcp; clamps keep saturation exact in fp32.
__device__ __forceinline__ float lstm_ew(float gi, float gf, float gg,
                                         float go, float& c){
  float Ef = EXP2(-gf);
  float Ei = EXP2(-gi);
  float gc = fminf(fmaxf(gg, -60.f), 60.f);
  float G  = EXP2(gc);
  float Rf = RCP(1.f + Ef);
  float Rig= RCP((1.f + Ei) * (1.f + G));
  c = c*Rf + (G - 1.f)*Rig;
  float Eo = EXP2(-go);
  float ch = fminf(fmaxf(c, -30.f), 30.f);
  float C2 = EXP2(ch * K2L);
  return (C2 - 1.f) * RCP((1.f + Eo) * (1.f + C2));
}

// R5: same single-barrier fused schedule and EW math as R4, re-decomposed to
// 512 blocks x 512 threads x 4 batch rows so TWO independent blocks co-reside
// per CU (block A's barrier/VALU tail overlaps block B's LDS burst).
// Tile-per-gate: wave owns all 4 gates of 16 units (4 tiles x 4 ksteps =
// 16 MFMA); the C-fragment holds all 4 gates x all 4 rows IN-LANE, so the
// DPP/ds_swizzle gate gather is gone (EW = 3 selects/gate + R4 chain).
// LDS strides 144/80 bf16 (72/40 dw == 8 mod 32): every read/store <=2-way.
extern "C" __global__ void __launch_bounds__(512, 4)
seq2seq_kernel(const float* __restrict__ X,
               const float* __restrict__ Wemb, const float* __restrict__ bemb,
               const float* __restrict__ eWih, const float* __restrict__ eWhh,
               const float* __restrict__ ebih, const float* __restrict__ ebhh,
               const float* __restrict__ dWih, const float* __restrict__ dWhh,
               const float* __restrict__ dbih, const float* __restrict__ dbhh,
               const float* __restrict__ Wreg, const float* __restrict__ breg,
               float* __restrict__ out)
{
  // XA[parity][row][144]: cols 0-63 = x/input, 64-127 = h0. h1 double-buffered.
  __shared__ __align__(16) __bf16 XA[2][4][144];
  __shared__ __align__(16) __bf16 H1s[2][4][80];

  const int tid  = (int)threadIdx.x;
  const int w    = tid >> 6;          // 0..7
  const bool g0  = (w < 4);           // waves 0-3: layer0, 4-7: layer1
  const int wt   = w & 3;             // wave-in-group; units 16*wt..+15
  const int lane = tid & 63;
  const int col  = lane & 15;
  const int quad = lane >> 4;
  const int r4   = col & 3;           // A real row (M=16 mirrors 4 rows)
  const int b0   = (int)blockIdx.x * 4;
  const int ucol = 16*wt + col;       // unit column 0..63
  const bool qb1 = (quad & 1) != 0;
  const bool qb2 = (quad & 2) != 0;

  for (int i = tid; i < 2*4*144; i += 512) (&XA[0][0][0])[i]  = (__bf16)0.f;
  for (int i = tid; i < 2*4*80;  i += 512) (&H1s[0][0][0])[i] = (__bf16)0.f;

  // ---- persistent weight fragments: 4 gate-tiles x 4 ksteps = 16 frags ----
  // gate col n = 64*gate + unit (PyTorch order i,f,g,o); gate == tile index.
  bf16x8 wf[16];
  float  gb[4];
#pragma unroll
  for (int ti=0; ti<4; ++ti){
    const int n = (g0 ? 0 : 256) + 64*ti + ucol;
    const float sc = (ti == 2) ? K2L : KL;
    gb[ti] = (ebih[n] + ebhh[n]) * sc;
#pragma unroll
    for (int ks=0; ks<4; ++ks){
      const float* srcw = (ks < 2) ? eWih : eWhh;
      wf[ti*4+ks] = ld8s(srcw + (size_t)n*64 + (ks&1)*32 + quad*8, sc);
    }
  }

  // emb fragments (grp0 waves, 16 emb cols each); single x prefetch pair,
  // distance 1 slot (slot I consumes x(I+2), then loads x(I+3)).
  bf16x8 wembf;
  float eb = 0.f;
  const float* xb = X + (size_t)(b0 + r4)*512*32 + quad*8;
  f32x4 pa, pb;
  if (g0){
    wembf = ld8(Wemb + ucol*32 + quad*8);
    eb = bemb[ucol];
    pa = *(const f32x4*)(xb+32); pb = *(const f32x4*)(xb+36);   // x(1)
  }

  float cC = 0.f;   // grp0: c0 of cell (row quad, unit ucol); grp1: c1

  // select reg index `quad` from an f32x4 without dynamic indexing
  auto pick = [&](f32x4 v) -> float {
    float s0 = qb2 ? v[2] : v[0];
    float s1 = qb2 ? v[3] : v[1];
    return qb1 ? s1 : s0;
  };

  // grp0 slot I: L0(I+1) gates+cell -> h0(I+1) at parity (I+1)&1;
  //              emb(I+2) -> XA[I&1].x
  auto FUSED0 = [&](const int I){
    const int Px = (I+1)&1, Pr = I&1;
    bf16x8 axe;
    if (I < 510){
      axe = cvt8(pa, pb);                       // x(I+2)
      int tn = I+3; if (tn > 511) tn = 511;     // prefetch x(I+3)
      pa = *(const f32x4*)(xb + (size_t)tn*32);
      pb = *(const f32x4*)(xb + (size_t)tn*32 + 4);
    }
    bf16x8 ax0 = *(const bf16x8*)&XA[Px][r4][ 0 + quad*8];
    bf16x8 ax1 = *(const bf16x8*)&XA[Px][r4][32 + quad*8];
    bf16x8 ah0 = *(const bf16x8*)&XA[Pr][r4][64 + quad*8];
    bf16x8 ah1 = *(const bf16x8*)&XA[Pr][r4][96 + quad*8];
    f32x4 A0 = sp(gb[0]), A1 = sp(gb[1]), A2 = sp(gb[2]), A3 = sp(gb[3]);
    A0=MFMA16(ax0,wf[ 0],A0); A1=MFMA16(ax0,wf[ 4],A1);
    A2=MFMA16(ax0,wf[ 8],A2); A3=MFMA16(ax0,wf[12],A3);
    A0=MFMA16(ax1,wf[ 1],A0); A1=MFMA16(ax1,wf[ 5],A1);
    A2=MFMA16(ax1,wf[ 9],A2); A3=MFMA16(ax1,wf[13],A3);
    A0=MFMA16(ah0,wf[ 2],A0); A1=MFMA16(ah0,wf[ 6],A1);
    A2=MFMA16(ah0,wf[10],A2); A3=MFMA16(ah0,wf[14],A3);
    A0=MFMA16(ah1,wf[ 3],A0); A1=MFMA16(ah1,wf[ 7],A1);
    A2=MFMA16(ah1,wf[11],A2); A3=MFMA16(ah1,wf[15],A3);
    if (I < 510){
      f32x4 ea = MFMA16(axe, wembf, sp(eb));    // emb(I+2), all quads equal
      if (quad == 0){
#pragma unroll
        for (int r=0; r<4; ++r) XA[I&1][r][ucol] = (__bf16)ea[r];
      }
    }
    XA[Px][quad][64+ucol] =
        (__bf16)lstm_ew(pick(A0), pick(A1), pick(A2), pick(A3), cC);
  };

  // grp1 slot I: L1(I) = [h0(I) | h1(I-1)] -> h1(I) at parity I&1
  auto FUSED1 = [&](const int I){
    const int Px = (I+1)&1, Pr = I&1;           // h1(I-1) parity == Px
    bf16x8 ah0 = *(const bf16x8*)&XA[Pr][r4][64 + quad*8];
    bf16x8 ah1 = *(const bf16x8*)&XA[Pr][r4][96 + quad*8];
    bf16x8 ag0 = *(const bf16x8*)&H1s[Px][r4][     quad*8];
    bf16x8 ag1 = *(const bf16x8*)&H1s[Px][r4][32 + quad*8];
    f32x4 A0 = sp(gb[0]), A1 = sp(gb[1]), A2 = sp(gb[2]), A3 = sp(gb[3]);
    A0=MFMA16(ah0,wf[ 0],A0); A1=MFMA16(ah0,wf[ 4],A1);
    A2=MFMA16(ah0,wf[ 8],A2); A3=MFMA16(ah0,wf[12],A3);
    A0=MFMA16(ah1,wf[ 1],A0); A1=MFMA16(ah1,wf[ 5],A1);
    A2=MFMA16(ah1,wf[ 9],A2); A3=MFMA16(ah1,wf[13],A3);
    A0=MFMA16(ag0,wf[ 2],A0); A1=MFMA16(ag0,wf[ 6],A1);
    A2=MFMA16(ag0,wf[10],A2); A3=MFMA16(ag0,wf[14],A3);
    A0=MFMA16(ag1,wf[ 3],A0); A1=MFMA16(ag1,wf[ 7],A1);
    A2=MFMA16(ag1,wf[11],A2); A3=MFMA16(ag1,wf[15],A3);
    H1s[Pr][quad][ucol] =
        (__bf16)lstm_ew(pick(A0), pick(A1), pick(A2), pick(A3), cC);
  };

  __syncthreads();                 // zero-init visible

  // ---- prologue: emb(0) from x(0), then h0(0) ----
  if (g0){
    f32x4 x0a = *(const f32x4*)xb, x0b = *(const f32x4*)(xb+4);
    f32x4 e0 = MFMA16(cvt8(x0a,x0b), wembf, sp(eb));
    if (quad == 0){
#pragma unroll
      for (int r=0; r<4; ++r) XA[0][r][ucol] = (__bf16)e0[r];
    }
  }
  __syncthreads();
  if (g0) FUSED0(-1);              // h0(0) -> parity 0; emb(1) -> XA[1].x
  __syncthreads();

  // ---- steady encoder: slot I -> h0(I+1) & h1(I); ONE barrier/slot ----
#define SLOT(I) { if (g0) FUSED0(I); else FUSED1(I); __syncthreads(); }
  for (int ii=0; ii<255; ++ii){
    SLOT(2*ii)
    SLOT(2*ii+1)
  }
  SLOT(510)
#undef SLOT

  // ---- epilogue: h1(511) ----
  if (!g0) FUSED1(511);            // reads h0(511) (par 1), h1(510) (par 0)
  __syncthreads();

  // ================= decoder =================
  // init: XA[1] = [input=h1(511) | h0(511)] (h0(511) already at XA[1][64..])
  for (int idx = tid; idx < 4*64; idx += 512)
    XA[1][idx>>6][idx&63] = H1s[1][idx>>6][idx&63];

  // decoder weights: waves 0-3 hold L0, waves 4-7 hold L1 (tile-per-gate)
  float gbd[4];
#pragma unroll
  for (int ti=0; ti<4; ++ti){
    const int n = (g0 ? 0 : 256) + 64*ti + ucol;
    const float sc = (ti == 2) ? K2L : KL;
    gbd[ti] = (dbih[n] + dbhh[n]) * sc;
#pragma unroll
    for (int ks=0; ks<4; ++ks){
      const float* srcw = (ks < 2) ? dWih : dWhh;
      wf[ti*4+ks] = ld8s(srcw + (size_t)n*64 + (ks&1)*32 + quad*8, sc);
    }
  }
  // regression head (unscaled)
  bf16x8 wr0 = ld8(Wreg + (col&7)*64 +      quad*8);
  bf16x8 wr1 = ld8(Wreg + (col&7)*64 + 32 + quad*8);
  const float rb = breg[col&7];
  float cD = 0.f;
  __syncthreads();

  auto Ystore = [&](const int t){
    const int hp = t&1;
    f32x4 ya = sp(rb);
    bf16x8 y0 = *(const bf16x8*)&H1s[hp][r4][     quad*8];
    bf16x8 y1 = *(const bf16x8*)&H1s[hp][r4][32 + quad*8];
    ya = MFMA16(y0, wr0, ya);
    ya = MFMA16(y1, wr1, ya);
    if (quad == 0 && col < 8){
#pragma unroll
      for (int r=0; r<4; ++r)
        out[((size_t)(b0 + r)*48 + t)*8 + col] = ya[r];
    }
  };

  // per step: P1 = L0 (waves 0-3) + Ystore (wave 4); P2 = L1 (waves 4-7)
  for (int t=0; t<48; ++t){
    const int P = t&1, Pm = P^1;
    if (g0){
      bf16x8 ax0 = *(const bf16x8*)&XA[Pm][r4][ 0 + quad*8];
      bf16x8 ax1 = *(const bf16x8*)&XA[Pm][r4][32 + quad*8];
      bf16x8 ah0 = *(const bf16x8*)&XA[Pm][r4][64 + quad*8];
      bf16x8 ah1 = *(const bf16x8*)&XA[Pm][r4][96 + quad*8];
      f32x4 A0 = sp(gbd[0]), A1 = sp(gbd[1]), A2 = sp(gbd[2]), A3 = sp(gbd[3]);
      A0=MFMA16(ax0,wf[ 0],A0); A1=MFMA16(ax0,wf[ 4],A1);
      A2=MFMA16(ax0,wf[ 8],A2); A3=MFMA16(ax0,wf[12],A3);
      A0=MFMA16(ax1,wf[ 1],A0); A1=MFMA16(ax1,wf[ 5],A1);
      A2=MFMA16(ax1,wf[ 9],A2); A3=MFMA16(ax1,wf[13],A3);
      A0=MFMA16(ah0,wf[ 2],A0); A1=MFMA16(ah0,wf[ 6],A1);
      A2=MFMA16(ah0,wf[10],A2); A3=MFMA16(ah0,wf[14],A3);
      A0=MFMA16(ah1,wf[ 3],A0); A1=MFMA16(ah1,wf[ 7],A1);
      A2=MFMA16(ah1,wf[11],A2); A3=MFMA16(ah1,wf[15],A3);
      XA[P][quad][64+ucol] =
          (__bf16)lstm_ew(pick(A0), pick(A1), pick(A2), pick(A3), cD);
    } else if (w == 4 && t) {
      Ystore(t-1);
    }
    __syncthreads();
    if (!g0){
      bf16x8 ah0 = *(const bf16x8*)&XA[P][r4][64 + quad*8];
      bf16x8 ah1 = *(const bf16x8*)&XA[P][r4][96 + quad*8];
      bf16x8 ag0 = *(const bf16x8*)&H1s[Pm][r4][     quad*8];
      bf16x8 ag1 = *(const bf16x8*)&H1s[Pm][r4][32 + quad*8];
      f32x4 A0 = sp(gbd[0]), A1 = sp(gbd[1]), A2 = sp(gbd[2]), A3 = sp(gbd[3]);
      A0=MFMA16(ah0,wf[ 0],A0); A1=MFMA16(ah0,wf[ 4],A1);
      A2=MFMA16(ah0,wf[ 8],A2); A3=MFMA16(ah0,wf[12],A3);
      A0=MFMA16(ah1,wf[ 1],A0); A1=MFMA16(ah1,wf[ 5],A1);
      A2=MFMA16(ah1,wf[ 9],A2); A3=MFMA16(ah1,wf[13],A3);
      A0=MFMA16(ag0,wf[ 2],A0); A1=MFMA16(ag0,wf[ 6],A1);
      A2=MFMA16(ag0,wf[10],A2); A3=MFMA16(ag0,wf[14],A3);
      A0=MFMA16(ag1,wf[ 3],A0); A1=MFMA16(ag1,wf[ 7],A1);
      A2=MFMA16(ag1,wf[11],A2); A3=MFMA16(ag1,wf[15],A3);
      float h = lstm_ew(pick(A0), pick(A1), pick(A2), pick(A3), cD);
      H1s[P][quad][ucol] = (__bf16)h;    // h1(t)
      XA[P][quad][ucol]  = (__bf16)h;    // feedback input(t+1)
    }
    __syncthreads();
  }
  if (w == 4) Ystore(47);
}

extern "C" void kernel_launch(void* const* d_in, const int* in_sizes, int n_in,
                              void* d_out, int out_size, void* d_ws, size_t ws_size,
                              hipStream_t stream)
{
  (void)in_sizes; (void)n_in; (void)out_size; (void)d_ws; (void)ws_size;
  const float* X    = (const float*)d_in[0];
  const float* Wemb = (const float*)d_in[2];
  const float* bemb = (const float*)d_in[3];
  const float* eWih = (const float*)d_in[4];
  const float* eWhh = (const float*)d_in[5];
  const float* ebih = (const float*)d_in[6];
  const float* ebhh = (const float*)d_in[7];
  const float* dWih = (const float*)d_in[8];
  const float* dWhh = (const float*)d_in[9];
  const float* dbih = (const float*)d_in[10];
  const float* dbhh = (const float*)d_in[11];
  const float* Wreg = (const float*)d_in[12];
  const float* breg = (const float*)d_in[13];
  float* out = (float*)d_out;

  seq2seq_kernel<<<dim3(512), dim3(512), 0, stream>>>(
      X, Wemb, bemb, eWih, eWhh, ebih, ebhh,
      dWih, dWhh, dbih, dbhh, Wreg, breg, out);
}

// Round 6
// 860.867 us; speedup vs baseline: 1.2683x; 1.2683x over previous
//
#include <hip/hip_runtime.h>
#include <hip/hip_bf16.h>

typedef __bf16 bf16x8 __attribute__((ext_vector_type(8)));
typedef float  f32x4  __attribute__((ext_vector_type(4)));

#define MFMA16(a,b,c) __builtin_amdgcn_mfma_f32_16x16x32_bf16((a),(b),(c),0,0,0)

#if __has_builtin(__builtin_amdgcn_exp2f)
#define EXP2(x) __builtin_amdgcn_exp2f(x)
#else
#define EXP2(x) exp2f(x)
#endif
#define RCP(x) __builtin_amdgcn_rcpf(x)

#define KL  1.44269504088896340736f   /* log2(e)   */
#define K2L 2.88539008177792681472f   /* 2*log2(e) */

__device__ __forceinline__ bf16x8 cvt8(f32x4 a, f32x4 b){
  bf16x8 r;
  r[0]=(__bf16)a[0]; r[1]=(__bf16)a[1]; r[2]=(__bf16)a[2]; r[3]=(__bf16)a[3];
  r[4]=(__bf16)b[0]; r[5]=(__bf16)b[1]; r[6]=(__bf16)b[2]; r[7]=(__bf16)b[3];
  return r;
}
__device__ __forceinline__ f32x4 sp(float v){ return (f32x4){v,v,v,v}; }
__device__ __forceinline__ bf16x8 ld8(const float* p){
  return cvt8(*(const f32x4*)p, *(const f32x4*)(p+4));
}
// scaled load: 8 f32 -> *s -> bf16x8  (gate weights pre-scaled by log2e)
__device__ __forceinline__ bf16x8 ld8s(const float* p, float s){
  f32x4 a = *(const f32x4*)p, b = *(const f32x4*)(p+4);
  return cvt8(a*sp(s), b*sp(s));
}

// LSTM elementwise with PRE-SCALED gates (validated R3/R4/R5, same absmax):
// 5 exp2 + 3 rcp; clamps keep saturation exact in fp32.
__device__ __forceinline__ float lstm_ew(float gi, float gf, float gg,
                                         float go, float& c){
  float Ef = EXP2(-gf);
  float Ei = EXP2(-gi);
  float gc = fminf(fmaxf(gg, -60.f), 60.f);
  float G  = EXP2(gc);
  float Rf = RCP(1.f + Ef);
  float Rig= RCP((1.f + Ei) * (1.f + G));
  c = c*Rf + (G - 1.f)*Rig;
  float Eo = EXP2(-go);
  float ch = fminf(fmaxf(c, -30.f), 30.f);
  float C2 = EXP2(ch * K2L);
  return (C2 - 1.f) * RCP((1.f + Eo) * (1.f + C2));
}

// R6 = R5 with the register cap fixed. R5's launch_bounds(512,4) acted as
// min-4-BLOCKS/CU (CUDA semantics) -> 32 waves/CU -> 64-VGPR cap -> the
// wf[16] (64 VGPR) design spilled to scratch (88 MB WRITE_SIZE, +39 MB FETCH,
// 958us). This kernel needs ~115 VGPR; (512,2) -> 16 waves/CU -> 128-VGPR
// cap, still 2 co-resident blocks/CU (the overlap R5 was designed for).
// Design recap: 512 blocks x 512 threads x 4 batch rows; single-barrier fused
// slot (L0(I+1) on waves 0-3 || L1(I) on waves 4-7); tile-per-gate so all 4
// gates of a cell sit IN-LANE (no cross-lane gather); strides 144/80 bf16
// measured conflict-free (R5: SQ_LDS_BANK_CONFLICT == 0).
extern "C" __global__ void __launch_bounds__(512, 2)
seq2seq_kernel(const float* __restrict__ X,
               const float* __restrict__ Wemb, const float* __restrict__ bemb,
               const float* __restrict__ eWih, const float* __restrict__ eWhh,
               const float* __restrict__ ebih, const float* __restrict__ ebhh,
               const float* __restrict__ dWih, const float* __restrict__ dWhh,
               const float* __restrict__ dbih, const float* __restrict__ dbhh,
               const float* __restrict__ Wreg, const float* __restrict__ breg,
               float* __restrict__ out)
{
  // XA[parity][row][144]: cols 0-63 = x/input, 64-127 = h0. h1 double-buffered.
  __shared__ __align__(16) __bf16 XA[2][4][144];
  __shared__ __align__(16) __bf16 H1s[2][4][80];

  const int tid  = (int)threadIdx.x;
  const int w    = tid >> 6;          // 0..7
  const bool g0  = (w < 4);           // waves 0-3: layer0, 4-7: layer1
  const int wt   = w & 3;             // wave-in-group; units 16*wt..+15
  const int lane = tid & 63;
  const int col  = lane & 15;
  const int quad = lane >> 4;
  const int r4   = col & 3;           // A real row (M=16 mirrors 4 rows)
  const int b0   = (int)blockIdx.x * 4;
  const int ucol = 16*wt + col;       // unit column 0..63
  const bool qb1 = (quad & 1) != 0;
  const bool qb2 = (quad & 2) != 0;

  for (int i = tid; i < 2*4*144; i += 512) (&XA[0][0][0])[i]  = (__bf16)0.f;
  for (int i = tid; i < 2*4*80;  i += 512) (&H1s[0][0][0])[i] = (__bf16)0.f;

  // ---- persistent weight fragments: 4 gate-tiles x 4 ksteps = 16 frags ----
  // gate col n = 64*gate + unit (PyTorch order i,f,g,o); gate == tile index.
  bf16x8 wf[16];
  float  gb[4];
#pragma unroll
  for (int ti=0; ti<4; ++ti){
    const int n = (g0 ? 0 : 256) + 64*ti + ucol;
    const float sc = (ti == 2) ? K2L : KL;
    gb[ti] = (ebih[n] + ebhh[n]) * sc;
#pragma unroll
    for (int ks=0; ks<4; ++ks){
      const float* srcw = (ks < 2) ? eWih : eWhh;
      wf[ti*4+ks] = ld8s(srcw + (size_t)n*64 + (ks&1)*32 + quad*8, sc);
    }
  }

  // emb fragments (grp0 waves, 16 emb cols each); single x prefetch pair,
  // distance 1 slot (slot I consumes x(I+2), then loads x(I+3)).
  bf16x8 wembf;
  float eb = 0.f;
  const float* xb = X + (size_t)(b0 + r4)*512*32 + quad*8;
  f32x4 pa, pb;
  if (g0){
    wembf = ld8(Wemb + ucol*32 + quad*8);
    eb = bemb[ucol];
    pa = *(const f32x4*)(xb+32); pb = *(const f32x4*)(xb+36);   // x(1)
  }

  float cC = 0.f;   // grp0: c0 of cell (row quad, unit ucol); grp1: c1

  // select reg index `quad` from an f32x4 without dynamic indexing
  auto pick = [&](f32x4 v) -> float {
    float s0 = qb2 ? v[2] : v[0];
    float s1 = qb2 ? v[3] : v[1];
    return qb1 ? s1 : s0;
  };

  // grp0 slot I: L0(I+1) gates+cell -> h0(I+1) at parity (I+1)&1;
  //              emb(I+2) -> XA[I&1].x
  auto FUSED0 = [&](const int I){
    const int Px = (I+1)&1, Pr = I&1;
    bf16x8 axe;
    if (I < 510){
      axe = cvt8(pa, pb);                       // x(I+2)
      int tn = I+3; if (tn > 511) tn = 511;     // prefetch x(I+3)
      pa = *(const f32x4*)(xb + (size_t)tn*32);
      pb = *(const f32x4*)(xb + (size_t)tn*32 + 4);
    }
    bf16x8 ax0 = *(const bf16x8*)&XA[Px][r4][ 0 + quad*8];
    bf16x8 ax1 = *(const bf16x8*)&XA[Px][r4][32 + quad*8];
    bf16x8 ah0 = *(const bf16x8*)&XA[Pr][r4][64 + quad*8];
    bf16x8 ah1 = *(const bf16x8*)&XA[Pr][r4][96 + quad*8];
    f32x4 A0 = sp(gb[0]), A1 = sp(gb[1]), A2 = sp(gb[2]), A3 = sp(gb[3]);
    A0=MFMA16(ax0,wf[ 0],A0); A1=MFMA16(ax0,wf[ 4],A1);
    A2=MFMA16(ax0,wf[ 8],A2); A3=MFMA16(ax0,wf[12],A3);
    A0=MFMA16(ax1,wf[ 1],A0); A1=MFMA16(ax1,wf[ 5],A1);
    A2=MFMA16(ax1,wf[ 9],A2); A3=MFMA16(ax1,wf[13],A3);
    A0=MFMA16(ah0,wf[ 2],A0); A1=MFMA16(ah0,wf[ 6],A1);
    A2=MFMA16(ah0,wf[10],A2); A3=MFMA16(ah0,wf[14],A3);
    A0=MFMA16(ah1,wf[ 3],A0); A1=MFMA16(ah1,wf[ 7],A1);
    A2=MFMA16(ah1,wf[11],A2); A3=MFMA16(ah1,wf[15],A3);
    if (I < 510){
      f32x4 ea = MFMA16(axe, wembf, sp(eb));    // emb(I+2), all quads equal
      if (quad == 0){
#pragma unroll
        for (int r=0; r<4; ++r) XA[I&1][r][ucol] = (__bf16)ea[r];
      }
    }
    XA[Px][quad][64+ucol] =
        (__bf16)lstm_ew(pick(A0), pick(A1), pick(A2), pick(A3), cC);
  };

  // grp1 slot I: L1(I) = [h0(I) | h1(I-1)] -> h1(I) at parity I&1
  auto FUSED1 = [&](const int I){
    const int Px = (I+1)&1, Pr = I&1;           // h1(I-1) parity == Px
    bf16x8 ah0 = *(const bf16x8*)&XA[Pr][r4][64 + quad*8];
    bf16x8 ah1 = *(const bf16x8*)&XA[Pr][r4][96 + quad*8];
    bf16x8 ag0 = *(const bf16x8*)&H1s[Px][r4][     quad*8];
    bf16x8 ag1 = *(const bf16x8*)&H1s[Px][r4][32 + quad*8];
    f32x4 A0 = sp(gb[0]), A1 = sp(gb[1]), A2 = sp(gb[2]), A3 = sp(gb[3]);
    A0=MFMA16(ah0,wf[ 0],A0); A1=MFMA16(ah0,wf[ 4],A1);
    A2=MFMA16(ah0,wf[ 8],A2); A3=MFMA16(ah0,wf[12],A3);
    A0=MFMA16(ah1,wf[ 1],A0); A1=MFMA16(ah1,wf[ 5],A1);
    A2=MFMA16(ah1,wf[ 9],A2); A3=MFMA16(ah1,wf[13],A3);
    A0=MFMA16(ag0,wf[ 2],A0); A1=MFMA16(ag0,wf[ 6],A1);
    A2=MFMA16(ag0,wf[10],A2); A3=MFMA16(ag0,wf[14],A3);
    A0=MFMA16(ag1,wf[ 3],A0); A1=MFMA16(ag1,wf[ 7],A1);
    A2=MFMA16(ag1,wf[11],A2); A3=MFMA16(ag1,wf[15],A3);
    H1s[Pr][quad][ucol] =
        (__bf16)lstm_ew(pick(A0), pick(A1), pick(A2), pick(A3), cC);
  };

  __syncthreads();                 // zero-init visible

  // ---- prologue: emb(0) from x(0), then h0(0) ----
  if (g0){
    f32x4 x0a = *(const f32x4*)xb, x0b = *(const f32x4*)(xb+4);
    f32x4 e0 = MFMA16(cvt8(x0a,x0b), wembf, sp(eb));
    if (quad == 0){
#pragma unroll
      for (int r=0; r<4; ++r) XA[0][r][ucol] = (__bf16)e0[r];
    }
  }
  __syncthreads();
  if (g0) FUSED0(-1);              // h0(0) -> parity 0; emb(1) -> XA[1].x
  __syncthreads();

  // ---- steady encoder: slot I -> h0(I+1) & h1(I); ONE barrier/slot ----
#define SLOT(I) { if (g0) FUSED0(I); else FUSED1(I); __syncthreads(); }
  for (int ii=0; ii<255; ++ii){
    SLOT(2*ii)
    SLOT(2*ii+1)
  }
  SLOT(510)
#undef SLOT

  // ---- epilogue: h1(511) ----
  if (!g0) FUSED1(511);            // reads h0(511) (par 1), h1(510) (par 0)
  __syncthreads();

  // ================= decoder =================
  // init: XA[1] = [input=h1(511) | h0(511)] (h0(511) already at XA[1][64..])
  for (int idx = tid; idx < 4*64; idx += 512)
    XA[1][idx>>6][idx&63] = H1s[1][idx>>6][idx&63];

  // decoder weights: waves 0-3 hold L0, waves 4-7 hold L1 (tile-per-gate)
  float gbd[4];
#pragma unroll
  for (int ti=0; ti<4; ++ti){
    const int n = (g0 ? 0 : 256) + 64*ti + ucol;
    const float sc = (ti == 2) ? K2L : KL;
    gbd[ti] = (dbih[n] + dbhh[n]) * sc;
#pragma unroll
    for (int ks=0; ks<4; ++ks){
      const float* srcw = (ks < 2) ? dWih : dWhh;
      wf[ti*4+ks] = ld8s(srcw + (size_t)n*64 + (ks&1)*32 + quad*8, sc);
    }
  }
  // regression head (unscaled)
  bf16x8 wr0 = ld8(Wreg + (col&7)*64 +      quad*8);
  bf16x8 wr1 = ld8(Wreg + (col&7)*64 + 32 + quad*8);
  const float rb = breg[col&7];
  float cD = 0.f;
  __syncthreads();

  auto Ystore = [&](const int t){
    const int hp = t&1;
    f32x4 ya = sp(rb);
    bf16x8 y0 = *(const bf16x8*)&H1s[hp][r4][     quad*8];
    bf16x8 y1 = *(const bf16x8*)&H1s[hp][r4][32 + quad*8];
    ya = MFMA16(y0, wr0, ya);
    ya = MFMA16(y1, wr1, ya);
    if (quad == 0 && col < 8){
#pragma unroll
      for (int r=0; r<4; ++r)
        out[((size_t)(b0 + r)*48 + t)*8 + col] = ya[r];
    }
  };

  // per step: P1 = L0 (waves 0-3) + Ystore (wave 4); P2 = L1 (waves 4-7)
  for (int t=0; t<48; ++t){
    const int P = t&1, Pm = P^1;
    if (g0){
      bf16x8 ax0 = *(const bf16x8*)&XA[Pm][r4][ 0 + quad*8];
      bf16x8 ax1 = *(const bf16x8*)&XA[Pm][r4][32 + quad*8];
      bf16x8 ah0 = *(const bf16x8*)&XA[Pm][r4][64 + quad*8];
      bf16x8 ah1 = *(const bf16x8*)&XA[Pm][r4][96 + quad*8];
      f32x4 A0 = sp(gbd[0]), A1 = sp(gbd[1]), A2 = sp(gbd[2]), A3 = sp(gbd[3]);
      A0=MFMA16(ax0,wf[ 0],A0); A1=MFMA16(ax0,wf[ 4],A1);
      A2=MFMA16(ax0,wf[ 8],A2); A3=MFMA16(ax0,wf[12],A3);
      A0=MFMA16(ax1,wf[ 1],A0); A1=MFMA16(ax1,wf[ 5],A1);
      A2=MFMA16(ax1,wf[ 9],A2); A3=MFMA16(ax1,wf[13],A3);
      A0=MFMA16(ah0,wf[ 2],A0); A1=MFMA16(ah0,wf[ 6],A1);
      A2=MFMA16(ah0,wf[10],A2); A3=MFMA16(ah0,wf[14],A3);
      A0=MFMA16(ah1,wf[ 3],A0); A1=MFMA16(ah1,wf[ 7],A1);
      A2=MFMA16(ah1,wf[11],A2); A3=MFMA16(ah1,wf[15],A3);
      XA[P][quad][64+ucol] =
          (__bf16)lstm_ew(pick(A0), pick(A1), pick(A2), pick(A3), cD);
    } else if (w == 4 && t) {
      Ystore(t-1);
    }
    __syncthreads();
    if (!g0){
      bf16x8 ah0 = *(const bf16x8*)&XA[P][r4][64 + quad*8];
      bf16x8 ah1 = *(const bf16x8*)&XA[P][r4][96 + quad*8];
      bf16x8 ag0 = *(const bf16x8*)&H1s[Pm][r4][     quad*8];
      bf16x8 ag1 = *(const bf16x8*)&H1s[Pm][r4][32 + quad*8];
      f32x4 A0 = sp(gbd[0]), A1 = sp(gbd[1]), A2 = sp(gbd[2]), A3 = sp(gbd[3]);
      A0=MFMA16(ah0,wf[ 0],A0); A1=MFMA16(ah0,wf[ 4],A1);
      A2=MFMA16(ah0,wf[ 8],A2); A3=MFMA16(ah0,wf[12],A3);
      A0=MFMA16(ah1,wf[ 1],A0); A1=MFMA16(ah1,wf[ 5],A1);
      A2=MFMA16(ah1,wf[ 9],A2); A3=MFMA16(ah1,wf[13],A3);
      A0=MFMA16(ag0,wf[ 2],A0); A1=MFMA16(ag0,wf[ 6],A1);
      A2=MFMA16(ag0,wf[10],A2); A3=MFMA16(ag0,wf[14],A3);
      A0=MFMA16(ag1,wf[ 3],A0); A1=MFMA16(ag1,wf[ 7],A1);
      A2=MFMA16(ag1,wf[11],A2); A3=MFMA16(ag1,wf[15],A3);
      float h = lstm_ew(pick(A0), pick(A1), pick(A2), pick(A3), cD);
      H1s[P][quad][ucol] = (__bf16)h;    // h1(t)
      XA[P][quad][ucol]  = (__bf16)h;    // feedback input(t+1)
    }
    __syncthreads();
  }
  if (w == 4) Ystore(47);
}

extern "C" void kernel_launch(void* const* d_in, const int* in_sizes, int n_in,
                              void* d_out, int out_size, void* d_ws, size_t ws_size,
                              hipStream_t stream)
{
  (void)in_sizes; (void)n_in; (void)out_size; (void)d_ws; (void)ws_size;
  const float* X    = (const float*)d_in[0];
  const float* Wemb = (const float*)d_in[2];
  const float* bemb = (const float*)d_in[3];
  const float* eWih = (const float*)d_in[4];
  const float* eWhh = (const float*)d_in[5];
  const float* ebih = (const float*)d_in[6];
  const float* ebhh = (const float*)d_in[7];
  const float* dWih = (const float*)d_in[8];
  const float* dWhh = (const float*)d_in[9];
  const float* dbih = (const float*)d_in[10];
  const float* dbhh = (const float*)d_in[11];
  const float* Wreg = (const float*)d_in[12];
  const float* breg = (const float*)d_in[13];
  float* out = (float*)d_out;

  seq2seq_kernel<<<dim3(512), dim3(512), 0, stream>>>(
      X, Wemb, bemb, eWih, eWhh, ebih, ebhh,
      dWih, dWhh, dbih, dbhh, Wreg, breg, out);
}

// Round 7
// 735.531 us; speedup vs baseline: 1.4844x; 1.1704x over previous
//
#include <hip/hip_runtime.h>
#include <hip/hip_bf16.h>

typedef __bf16 bf16x8 __attribute__((ext_vector_type(8)));
typedef float  f32x4  __attribute__((ext_vector_type(4)));

#define MFMA16(a,b,c) __builtin_amdgcn_mfma_f32_16x16x32_bf16((a),(b),(c),0,0,0)

#if __has_builtin(__builtin_amdgcn_exp2f)
#define EXP2(x) __builtin_amdgcn_exp2f(x)
#else
#define EXP2(x) exp2f(x)
#endif
#define RCP(x) __builtin_amdgcn_rcpf(x)

#define KL  1.44269504088896340736f   /* log2(e)   */
#define K2L 2.88539008177792681472f   /* 2*log2(e) */

__device__ __forceinline__ bf16x8 cvt8(f32x4 a, f32x4 b){
  bf16x8 r;
  r[0]=(__bf16)a[0]; r[1]=(__bf16)a[1]; r[2]=(__bf16)a[2]; r[3]=(__bf16)a[3];
  r[4]=(__bf16)b[0]; r[5]=(__bf16)b[1]; r[6]=(__bf16)b[2]; r[7]=(__bf16)b[3];
  return r;
}
__device__ __forceinline__ f32x4 sp(float v){ return (f32x4){v,v,v,v}; }
__device__ __forceinline__ bf16x8 ld8(const float* p){
  return cvt8(*(const f32x4*)p, *(const f32x4*)(p+4));
}
// scaled load: 8 f32 -> *s -> bf16x8  (gate weights pre-scaled by log2e)
__device__ __forceinline__ bf16x8 ld8s(const float* p, float s){
  f32x4 a = *(const f32x4*)p, b = *(const f32x4*)(p+4);
  return cvt8(a*sp(s), b*sp(s));
}

// LSTM elementwise with PRE-SCALED gates (validated R3-R6, same absmax):
// 5 exp2 + 3 rcp; clamps keep saturation exact in fp32.
__device__ __forceinline__ float lstm_ew(float gi, float gf, float gg,
                                         float go, float& c){
  float Ef = EXP2(-gf);
  float Ei = EXP2(-gi);
  float gc = fminf(fmaxf(gg, -60.f), 60.f);
  float G  = EXP2(gc);
  float Rf = RCP(1.f + Ef);
  float Rig= RCP((1.f + Ei) * (1.f + G));
  c = c*Rf + (G - 1.f)*Rig;
  float Eo = EXP2(-go);
  float ch = fminf(fmaxf(c, -30.f), 30.f);
  float C2 = EXP2(ch * K2L);
  return (C2 - 1.f) * RCP((1.f + Eo) * (1.f + C2));
}

// R7 = R6 + register diet to make 2 blocks/CU actually fit.
// Model from R0-R6 counters: launch_bounds arg2 = min waves/EU; reg budget =
// 512/arg2 TOTAL (unified VGPR+AGPR); compiler parks the 16 weight frags (64
// regs) in AGPRs. R6's (512,2) -> budget 256 -> alloc 160/wave -> 3 waves/EU
// -> only 1 block resident (Occupancy 23.5%) -> no overlap, 706us.
// Diet: (a) Wemb folded into L0 input weights (K=32, validated R3): grp0 wf
// 16->12 frags, emb MFMA + wembf/eb gone, x comes from regs (no x-LDS reads:
// 24 b128/block/slot, -25%); (b) x prefetch as one bf16x8 (4 regs, not 8).
// Need ~= 64 AGPR + ~60 arch ~= 124 <= 128 = budget of (512,4) -> 4 waves/EU
// -> TWO co-resident 8-wave blocks/CU, anti-phased by independent barriers.
extern "C" __global__ void __launch_bounds__(512, 4)
seq2seq_kernel(const float* __restrict__ X,
               const float* __restrict__ Wemb, const float* __restrict__ bemb,
               const float* __restrict__ eWih, const float* __restrict__ eWhh,
               const float* __restrict__ ebih, const float* __restrict__ ebhh,
               const float* __restrict__ dWih, const float* __restrict__ dWhh,
               const float* __restrict__ dbih, const float* __restrict__ dbhh,
               const float* __restrict__ Wreg, const float* __restrict__ breg,
               float* __restrict__ out)
{
  // XA[parity][row][144]: cols 0-63 = decoder input, 64-127 = h0.
  // h1 double-buffered. Strides 144/80 bf16: measured conflict-free (R5/R6).
  __shared__ __align__(16) __bf16 XA[2][4][144];
  __shared__ __align__(16) __bf16 H1s[2][4][80];

  const int tid  = (int)threadIdx.x;
  const int w    = tid >> 6;          // 0..7
  const bool g0  = (w < 4);           // waves 0-3: layer0, 4-7: layer1
  const int wt   = w & 3;             // wave-in-group; units 16*wt..+15
  const int lane = tid & 63;
  const int col  = lane & 15;
  const int quad = lane >> 4;
  const int r4   = col & 3;           // A real row (M=16 mirrors 4 rows)
  const int b0   = (int)blockIdx.x * 4;
  const int ucol = 16*wt + col;       // unit column 0..63
  const bool qb1 = (quad & 1) != 0;
  const bool qb2 = (quad & 2) != 0;

  for (int i = tid; i < 2*4*144; i += 512) (&XA[0][0][0])[i]  = (__bf16)0.f;
  for (int i = tid; i < 2*4*80;  i += 512) (&H1s[0][0][0])[i] = (__bf16)0.f;

  // ---- persistent weight fragments ----
  // gate col n = 64*gate + unit (PyTorch i,f,g,o); gate == tile index.
  // grp0: wf[ti*4+0] = W' x-frag (K=32, Wemb folded), wf[ti*4+2/3] = Whh.
  //       wf[ti*4+1] unused (never written/read -> no reg cost).
  // grp1: wf[ti*4+0..3] = [Wih | Whh] K=128.
  bf16x8 wf[16];
  float  gb[4];
  if (g0){
#pragma unroll
    for (int ti=0; ti<4; ++ti){
      const int n = 64*ti + ucol;
      const float sc = (ti == 2) ? K2L : KL;
      // fold: W'[n][f] = sum_k eWih0[n][k]*Wemb[k][f];  bx = eWih0[n]@bemb
      f32x4 acL = sp(0.f), acH = sp(0.f);
      float bx = ebih[n] + ebhh[n];
      const float* wr_ = eWih + (size_t)n*64;
      for (int k=0; k<64; ++k){
        float a = wr_[k];
        bx += a * bemb[k];
        acL += sp(a) * *(const f32x4*)(Wemb + k*32 + quad*8);
        acH += sp(a) * *(const f32x4*)(Wemb + k*32 + quad*8 + 4);
      }
      wf[ti*4+0] = cvt8(acL*sp(sc), acH*sp(sc));
      wf[ti*4+2] = ld8s(eWhh + (size_t)n*64 +      quad*8, sc);
      wf[ti*4+3] = ld8s(eWhh + (size_t)n*64 + 32 + quad*8, sc);
      gb[ti] = bx * sc;
    }
  } else {
#pragma unroll
    for (int ti=0; ti<4; ++ti){
      const int n = 256 + 64*ti + ucol;
      const float sc = (ti == 2) ? K2L : KL;
      gb[ti] = (ebih[n] + ebhh[n]) * sc;
#pragma unroll
      for (int ks=0; ks<4; ++ks){
        const float* srcw = (ks < 2) ? eWih : eWhh;
        wf[ti*4+ks] = ld8s(srcw + (size_t)n*64 + (ks&1)*32 + quad*8, sc);
      }
    }
  }

  // x held in regs as ONE bf16x8 (grp0): xcur = x(I+1) at slot-I entry.
  const float* xb = X + (size_t)(b0 + r4)*512*32 + quad*8;
  bf16x8 xcur;
  if (g0){
    f32x4 xa = *(const f32x4*)xb, xbv = *(const f32x4*)(xb+4);   // x(0)
    xcur = cvt8(xa, xbv);
  }

  float cC = 0.f;   // grp0: c0 of cell (row quad, unit ucol); grp1: c1

  // select reg index `quad` from an f32x4 without dynamic indexing
  auto pick = [&](f32x4 v) -> float {
    float s0 = qb2 ? v[2] : v[0];
    float s1 = qb2 ? v[3] : v[1];
    return qb1 ? s1 : s0;
  };

  // grp0 slot I: L0(I+1) from x(I+1)[regs] & h0(I)[LDS] -> h0(I+1);
  //              prefetch x(I+2) into xcur. 12 MFMAs.
  auto FUSED0 = [&](const int I){
    const int Px = (I+1)&1, Pr = I&1;
    bf16x8 axf = xcur;
    { int tn = I+2; if (tn > 511) tn = 511;
      f32x4 na = *(const f32x4*)(xb + (size_t)tn*32);
      f32x4 nb = *(const f32x4*)(xb + (size_t)tn*32 + 4);
      xcur = cvt8(na, nb);
    }
    bf16x8 ah0 = *(const bf16x8*)&XA[Pr][r4][64 + quad*8];
    bf16x8 ah1 = *(const bf16x8*)&XA[Pr][r4][96 + quad*8];
    f32x4 A0 = sp(gb[0]), A1 = sp(gb[1]), A2 = sp(gb[2]), A3 = sp(gb[3]);
    A0=MFMA16(axf,wf[ 0],A0); A1=MFMA16(axf,wf[ 4],A1);
    A2=MFMA16(axf,wf[ 8],A2); A3=MFMA16(axf,wf[12],A3);
    A0=MFMA16(ah0,wf[ 2],A0); A1=MFMA16(ah0,wf[ 6],A1);
    A2=MFMA16(ah0,wf[10],A2); A3=MFMA16(ah0,wf[14],A3);
    A0=MFMA16(ah1,wf[ 3],A0); A1=MFMA16(ah1,wf[ 7],A1);
    A2=MFMA16(ah1,wf[11],A2); A3=MFMA16(ah1,wf[15],A3);
    XA[Px][quad][64+ucol] =
        (__bf16)lstm_ew(pick(A0), pick(A1), pick(A2), pick(A3), cC);
  };

  // grp1 slot I: L1(I) = [h0(I) | h1(I-1)] -> h1(I) at parity I&1. 16 MFMAs.
  auto FUSED1 = [&](const int I){
    const int Px = (I+1)&1, Pr = I&1;           // h1(I-1) parity == Px
    bf16x8 ah0 = *(const bf16x8*)&XA[Pr][r4][64 + quad*8];
    bf16x8 ah1 = *(const bf16x8*)&XA[Pr][r4][96 + quad*8];
    bf16x8 ag0 = *(const bf16x8*)&H1s[Px][r4][     quad*8];
    bf16x8 ag1 = *(const bf16x8*)&H1s[Px][r4][32 + quad*8];
    f32x4 A0 = sp(gb[0]), A1 = sp(gb[1]), A2 = sp(gb[2]), A3 = sp(gb[3]);
    A0=MFMA16(ah0,wf[ 0],A0); A1=MFMA16(ah0,wf[ 4],A1);
    A2=MFMA16(ah0,wf[ 8],A2); A3=MFMA16(ah0,wf[12],A3);
    A0=MFMA16(ah1,wf[ 1],A0); A1=MFMA16(ah1,wf[ 5],A1);
    A2=MFMA16(ah1,wf[ 9],A2); A3=MFMA16(ah1,wf[13],A3);
    A0=MFMA16(ag0,wf[ 2],A0); A1=MFMA16(ag0,wf[ 6],A1);
    A2=MFMA16(ag0,wf[10],A2); A3=MFMA16(ag0,wf[14],A3);
    A0=MFMA16(ag1,wf[ 3],A0); A1=MFMA16(ag1,wf[ 7],A1);
    A2=MFMA16(ag1,wf[11],A2); A3=MFMA16(ag1,wf[15],A3);
    H1s[Pr][quad][ucol] =
        (__bf16)lstm_ew(pick(A0), pick(A1), pick(A2), pick(A3), cC);
  };

  __syncthreads();                 // zero-init visible

  // ---- prologue: L0(0) from x(0), h0(-1)=0 ----
  if (g0) FUSED0(-1);              // h0(0) -> parity 0
  __syncthreads();

  // ---- steady encoder: slot I -> h0(I+1) & h1(I); ONE barrier/slot ----
#define SLOT(I) { if (g0) FUSED0(I); else FUSED1(I); __syncthreads(); }
  for (int ii=0; ii<255; ++ii){
    SLOT(2*ii)
    SLOT(2*ii+1)
  }
  SLOT(510)
#undef SLOT

  // ---- epilogue: h1(511) ----
  if (!g0) FUSED1(511);            // reads h0(511) (par 1), h1(510) (par 0)
  __syncthreads();

  // ================= decoder (verbatim R6, measured conflict-free) =========
  // init: XA[1] = [input=h1(511) | h0(511)] (h0(511) already at XA[1][64..])
  for (int idx = tid; idx < 4*64; idx += 512)
    XA[1][idx>>6][idx&63] = H1s[1][idx>>6][idx&63];

  // decoder weights: waves 0-3 hold L0, waves 4-7 hold L1 (tile-per-gate)
  float gbd[4];
#pragma unroll
  for (int ti=0; ti<4; ++ti){
    const int n = (g0 ? 0 : 256) + 64*ti + ucol;
    const float sc = (ti == 2) ? K2L : KL;
    gbd[ti] = (dbih[n] + dbhh[n]) * sc;
#pragma unroll
    for (int ks=0; ks<4; ++ks){
      const float* srcw = (ks < 2) ? dWih : dWhh;
      wf[ti*4+ks] = ld8s(srcw + (size_t)n*64 + (ks&1)*32 + quad*8, sc);
    }
  }
  // regression head (unscaled)
  bf16x8 wr0 = ld8(Wreg + (col&7)*64 +      quad*8);
  bf16x8 wr1 = ld8(Wreg + (col&7)*64 + 32 + quad*8);
  const float rb = breg[col&7];
  float cD = 0.f;
  __syncthreads();

  auto Ystore = [&](const int t){
    const int hp = t&1;
    f32x4 ya = sp(rb);
    bf16x8 y0 = *(const bf16x8*)&H1s[hp][r4][     quad*8];
    bf16x8 y1 = *(const bf16x8*)&H1s[hp][r4][32 + quad*8];
    ya = MFMA16(y0, wr0, ya);
    ya = MFMA16(y1, wr1, ya);
    if (quad == 0 && col < 8){
#pragma unroll
      for (int r=0; r<4; ++r)
        out[((size_t)(b0 + r)*48 + t)*8 + col] = ya[r];
    }
  };

  // per step: P1 = L0 (waves 0-3) + Ystore (wave 4); P2 = L1 (waves 4-7)
  for (int t=0; t<48; ++t){
    const int P = t&1, Pm = P^1;
    if (g0){
      bf16x8 ax0 = *(const bf16x8*)&XA[Pm][r4][ 0 + quad*8];
      bf16x8 ax1 = *(const bf16x8*)&XA[Pm][r4][32 + quad*8];
      bf16x8 ah0 = *(const bf16x8*)&XA[Pm][r4][64 + quad*8];
      bf16x8 ah1 = *(const bf16x8*)&XA[Pm][r4][96 + quad*8];
      f32x4 A0 = sp(gbd[0]), A1 = sp(gbd[1]), A2 = sp(gbd[2]), A3 = sp(gbd[3]);
      A0=MFMA16(ax0,wf[ 0],A0); A1=MFMA16(ax0,wf[ 4],A1);
      A2=MFMA16(ax0,wf[ 8],A2); A3=MFMA16(ax0,wf[12],A3);
      A0=MFMA16(ax1,wf[ 1],A0); A1=MFMA16(ax1,wf[ 5],A1);
      A2=MFMA16(ax1,wf[ 9],A2); A3=MFMA16(ax1,wf[13],A3);
      A0=MFMA16(ah0,wf[ 2],A0); A1=MFMA16(ah0,wf[ 6],A1);
      A2=MFMA16(ah0,wf[10],A2); A3=MFMA16(ah0,wf[14],A3);
      A0=MFMA16(ah1,wf[ 3],A0); A1=MFMA16(ah1,wf[ 7],A1);
      A2=MFMA16(ah1,wf[11],A2); A3=MFMA16(ah1,wf[15],A3);
      XA[P][quad][64+ucol] =
          (__bf16)lstm_ew(pick(A0), pick(A1), pick(A2), pick(A3), cD);
    } else if (w == 4 && t) {
      Ystore(t-1);
    }
    __syncthreads();
    if (!g0){
      bf16x8 ah0 = *(const bf16x8*)&XA[P][r4][64 + quad*8];
      bf16x8 ah1 = *(const bf16x8*)&XA[P][r4][96 + quad*8];
      bf16x8 ag0 = *(const bf16x8*)&H1s[Pm][r4][     quad*8];
      bf16x8 ag1 = *(const bf16x8*)&H1s[Pm][r4][32 + quad*8];
      f32x4 A0 = sp(gbd[0]), A1 = sp(gbd[1]), A2 = sp(gbd[2]), A3 = sp(gbd[3]);
      A0=MFMA16(ah0,wf[ 0],A0); A1=MFMA16(ah0,wf[ 4],A1);
      A2=MFMA16(ah0,wf[ 8],A2); A3=MFMA16(ah0,wf[12],A3);
      A0=MFMA16(ah1,wf[ 1],A0); A1=MFMA16(ah1,wf[ 5],A1);
      A2=MFMA16(ah1,wf[ 9],A2); A3=MFMA16(ah1,wf[13],A3);
      A0=MFMA16(ag0,wf[ 2],A0); A1=MFMA16(ag0,wf[ 6],A1);
      A2=MFMA16(ag0,wf[10],A2); A3=MFMA16(ag0,wf[14],A3);
      A0=MFMA16(ag1,wf[ 3],A0); A1=MFMA16(ag1,wf[ 7],A1);
      A2=MFMA16(ag1,wf[11],A2); A3=MFMA16(ag1,wf[15],A3);
      float h = lstm_ew(pick(A0), pick(A1), pick(A2), pick(A3), cD);
      H1s[P][quad][ucol] = (__bf16)h;    // h1(t)
      XA[P][quad][ucol]  = (__bf16)h;    // feedback input(t+1)
    }
    __syncthreads();
  }
  if (w == 4) Ystore(47);
}

extern "C" void kernel_launch(void* const* d_in, const int* in_sizes, int n_in,
                              void* d_out, int out_size, void* d_ws, size_t ws_size,
                              hipStream_t stream)
{
  (void)in_sizes; (void)n_in; (void)out_size; (void)d_ws; (void)ws_size;
  const float* X    = (const float*)d_in[0];
  const float* Wemb = (const float*)d_in[2];
  const float* bemb = (const float*)d_in[3];
  const float* eWih = (const float*)d_in[4];
  const float* eWhh = (const float*)d_in[5];
  const float* ebih = (const float*)d_in[6];
  const float* ebhh = (const float*)d_in[7];
  const float* dWih = (const float*)d_in[8];
  const float* dWhh = (const float*)d_in[9];
  const float* dbih = (const float*)d_in[10];
  const float* dbhh = (const float*)d_in[11];
  const float* Wreg = (const float*)d_in[12];
  const float* breg = (const float*)d_in[13];
  float* out = (float*)d_out;

  seq2seq_kernel<<<dim3(512), dim3(512), 0, stream>>>(
      X, Wemb, bemb, eWih, eWhh, ebih, ebhh,
      dWih, dWhh, dbih, dbhh, Wreg, breg, out);
}